// Round 1
// baseline (6459.963 us; speedup 1.0000x reference)
//
#include <hip/hip_runtime.h>
#include <math.h>

#define B_    4096
#define L_    16
#define E_    50
#define H_    512
#define G4_   2048   // 4*H
#define V_    128
#define VIS_  2048

// ---------------------------------------------------------------- lengths
__global__ void lengths_k(const int* __restrict__ text, int* __restrict__ lens) {
  int b = blockIdx.x * blockDim.x + threadIdx.x;
  if (b < B_) {
    int c = 0;
    for (int t = 0; t < L_; ++t) c += (text[b * L_ + t] != 0) ? 1 : 0;
    lens[b] = c;
  }
}

// ------------------------------------------------- embedding staging (enc+dec)
// layout [t][b][e]
__global__ void stage_embs_k(const int* __restrict__ text, const float* __restrict__ emb,
                             float* __restrict__ xs_enc, float* __restrict__ xs_dec) {
  int idx = blockIdx.x * blockDim.x + threadIdx.x;
  const int total = L_ * B_ * E_;
  if (idx >= total) return;
  int e = idx % E_;
  int r = idx / E_;
  int b = r % B_;
  int t = r / B_;
  int id_enc = text[b * L_ + t];
  int id_dec = (t == 0) ? 0 : text[b * L_ + t - 1];
  xs_enc[idx] = emb[id_enc * E_ + e];
  xs_dec[idx] = emb[id_dec * E_ + e];
}

__global__ void fill_k(float* __restrict__ p, float v, int n) {
  int i = blockIdx.x * blockDim.x + threadIdx.x;
  if (i < n) p[i] = v;
}

__global__ void copy_k(float* __restrict__ dst, const float* __restrict__ src, int n) {
  int i = blockIdx.x * blockDim.x + threadIdx.x;
  if (i < n) dst[i] = src[i];
}

// ---------------------------------------------------------------- NT GEMM
// C[m,n] = sum_k A1[m,k]*B1[n,k]  (+ sum_k A2[m,k]*B2[n,k])  (+bias1[n]+bias2[n]) (relu?)
// A row-major [M,lda], B row-major [N,ldb]. M,N must be multiples of 64.
__global__ __launch_bounds__(256)
void gemm_nt_k(const float* __restrict__ A1, int lda1,
               const float* __restrict__ B1, int ldb1, int K1,
               const float* __restrict__ A2, int lda2,
               const float* __restrict__ B2, int ldb2, int K2,
               const float* __restrict__ bias1, const float* __restrict__ bias2,
               float* __restrict__ C, int ldc, int relu) {
  __shared__ float As[16][68];
  __shared__ float Bs[16][68];
  const int tid = threadIdx.x;
  const int m0 = blockIdx.y * 64;
  const int n0 = blockIdx.x * 64;
  const int tr = tid >> 4;   // 0..15
  const int tc = tid & 15;   // 0..15
  float acc[4][4] = {};

  auto seg = [&](const float* __restrict__ A, int lda,
                 const float* __restrict__ Bp, int ldb, int K) {
    for (int k0 = 0; k0 < K; k0 += 16) {
#pragma unroll
      for (int l = 0; l < 4; ++l) {
        int e = tid + 256 * l;       // 0..1023
        int m = e >> 4;
        int k = e & 15;
        float val = 0.f;
        if (k0 + k < K) val = A[(size_t)(m0 + m) * lda + k0 + k];
        As[k][m] = val;
      }
#pragma unroll
      for (int l = 0; l < 4; ++l) {
        int e = tid + 256 * l;
        int n = e >> 4;
        int k = e & 15;
        float val = 0.f;
        if (k0 + k < K) val = Bp[(size_t)(n0 + n) * ldb + k0 + k];
        Bs[k][n] = val;
      }
      __syncthreads();
#pragma unroll
      for (int kk = 0; kk < 16; ++kk) {
        float a[4], bv[4];
#pragma unroll
        for (int i = 0; i < 4; ++i) a[i] = As[kk][tr * 4 + i];
#pragma unroll
        for (int j = 0; j < 4; ++j) bv[j] = Bs[kk][tc * 4 + j];
#pragma unroll
        for (int i = 0; i < 4; ++i)
#pragma unroll
          for (int j = 0; j < 4; ++j) acc[i][j] += a[i] * bv[j];
      }
      __syncthreads();
    }
  };
  seg(A1, lda1, B1, ldb1, K1);
  if (A2) seg(A2, lda2, B2, ldb2, K2);

#pragma unroll
  for (int i = 0; i < 4; ++i) {
    int m = m0 + tr * 4 + i;
#pragma unroll
    for (int j = 0; j < 4; ++j) {
      int n = n0 + tc * 4 + j;
      float v = acc[i][j];
      if (bias1) v += bias1[n];
      if (bias2) v += bias2[n];
      if (relu) v = fmaxf(v, 0.f);
      C[(size_t)m * ldc + n] = v;
    }
  }
}

// ---------------------------------------------------------------- LSTM cell
// gates [B,4H] order i,f,g,o. In-place c,h update. Optional select at t==len-1.
__global__ void lstm_update_k(const float* __restrict__ gates, float* __restrict__ c,
                              float* __restrict__ h, float* __restrict__ sel,
                              const int* __restrict__ lens, int t) {
  int idx = blockIdx.x * blockDim.x + threadIdx.x;
  if (idx >= B_ * H_) return;
  int b = idx / H_;
  int j = idx - b * H_;
  const float* g = gates + (size_t)b * G4_;
  float ig = g[j], fg = g[H_ + j], gg = g[2 * H_ + j], og = g[3 * H_ + j];
  float si = 1.f / (1.f + expf(-ig));
  float sf = 1.f / (1.f + expf(-fg));
  float so = 1.f / (1.f + expf(-og));
  float tg = tanhf(gg);
  float cn = sf * c[idx] + si * tg;
  float hn = so * tanhf(cn);
  c[idx] = cn;
  h[idx] = hn;
  if (sel != nullptr) {
    int len = lens[b];
    int eff = (len == 0) ? L_ : len;   // jnp outs[-1] wraps to last step
    if (t == eff - 1) sel[idx] = hn;
  }
}

// ---------------------------------------------------------------- row L2-normalize
__global__ void rownorm_k(float* __restrict__ x, int n) {
  int b = blockIdx.x;
  int tid = threadIdx.x;
  float* row = x + (size_t)b * n;
  float s = 0.f;
  for (int i = tid; i < n; i += 256) { float v = row[i]; s += v * v; }
  __shared__ float red[256];
  red[tid] = s;
  __syncthreads();
  for (int st = 128; st > 0; st >>= 1) {
    if (tid < st) red[tid] += red[tid + st];
    __syncthreads();
  }
  float inv = 1.f / sqrtf(red[0]);
  for (int i = tid; i < n; i += 256) row[i] *= inv;
}

// ---------------------------------------------------------------- row softmax (P rows)
__global__ void softmax_rows_k(float* __restrict__ P, int n) {
  int r = blockIdx.x;
  int tid = threadIdx.x;
  float* row = P + (size_t)r * n;
  __shared__ float red[256];
  float m = -1e30f;
  for (int i = tid; i < n; i += 256) m = fmaxf(m, row[i]);
  red[tid] = m;
  __syncthreads();
  for (int st = 128; st > 0; st >>= 1) {
    if (tid < st) red[tid] = fmaxf(red[tid], red[tid + st]);
    __syncthreads();
  }
  m = red[0];
  __syncthreads();
  float s = 0.f;
  for (int i = tid; i < n; i += 256) { float e = expf(row[i] - m); row[i] = e; s += e; }
  red[tid] = s;
  __syncthreads();
  for (int st = 128; st > 0; st >>= 1) {
    if (tid < st) red[tid] += red[tid + st];
    __syncthreads();
  }
  float inv = 1.f / red[0];
  for (int i = tid; i < n; i += 256) row[i] *= inv;
}

// ---------------------------------------------------------------- transpose out[c][r]=in[r][c]
__global__ void transpose_k(const float* __restrict__ in, float* __restrict__ out,
                            int R, int Ccols) {
  __shared__ float tile[32][33];
  int c0 = blockIdx.x * 32, r0 = blockIdx.y * 32;
  int tx = threadIdx.x & 31, ty = threadIdx.x >> 5;  // 256 threads: ty 0..7
  for (int i = ty; i < 32; i += 8) tile[i][tx] = in[(size_t)(r0 + i) * Ccols + c0 + tx];
  __syncthreads();
  for (int i = ty; i < 32; i += 8) out[(size_t)(c0 + i) * R + r0 + tx] = tile[tx][i];
}

// ---------------------------------------------------------------- decoder logits + NLL
// WoutT is [H,V] (= W_out transposed). out[b] (+)= loss/L.
__global__ __launch_bounds__(128)
void dec_loss_k(const float* __restrict__ hs, const float* __restrict__ WoutT,
                const int* __restrict__ text, int t, float* __restrict__ out) {
  int b = blockIdx.x;
  int v = threadIdx.x;  // 0..127
  __shared__ float hrow[H_];
  __shared__ float lg[V_];
  __shared__ float red[V_];
  for (int i = v; i < H_; i += 128) hrow[i] = hs[(size_t)b * H_ + i];
  __syncthreads();
  float acc = 0.f;
  for (int k = 0; k < H_; ++k) acc += hrow[k] * WoutT[(size_t)k * V_ + v];
  lg[v] = acc;
  red[v] = acc;
  __syncthreads();
  for (int st = 64; st > 0; st >>= 1) {
    if (v < st) red[v] = fmaxf(red[v], red[v + st]);
    __syncthreads();
  }
  float mx = red[0];
  __syncthreads();
  red[v] = expf(acc - mx);
  __syncthreads();
  for (int st = 64; st > 0; st >>= 1) {
    if (v < st) red[v] += red[v + st];
    __syncthreads();
  }
  if (v == 0) {
    float lse = mx + logf(red[0]);
    int tgt = text[b * L_ + t];
    float loss = (lse - lg[tgt]) / (float)L_;
    if (t == 0) out[b] = loss;
    else out[b] += loss;
  }
}

// ================================================================ launch
extern "C" void kernel_launch(void* const* d_in, const int* in_sizes, int n_in,
                              void* d_out, int out_size, void* d_ws, size_t ws_size,
                              hipStream_t stream) {
  const float* visual = (const float*)d_in[0];   // [B,1,VIS]
  const int*   text   = (const int*)  d_in[1];   // [B,L]
  const float* emb    = (const float*)d_in[2];   // [V,E]
  const float* W_ih   = (const float*)d_in[3];   // [4H,E]
  const float* W_hh   = (const float*)d_in[4];   // [4H,H]
  const float* b_ih   = (const float*)d_in[5];   // [4H]
  const float* b_hh   = (const float*)d_in[6];   // [4H]
  const float* W_enc  = (const float*)d_in[7];   // [H,H]
  const float* b_enc  = (const float*)d_in[8];   // [H]
  const float* W_out  = (const float*)d_in[9];   // [V,H]
  const float* W_vis  = (const float*)d_in[10];  // [H,VIS]
  float* out = (float*)d_out;

  float* ws = (float*)d_ws;
  size_t off = 0;
  float* xs_enc = ws + off; off += (size_t)L_ * B_ * E_;   // 3,276,800
  float* xs_dec = ws + off; off += (size_t)L_ * B_ * E_;
  float* v      = ws + off; off += (size_t)B_ * H_;        // 2,097,152
  float* h      = ws + off; off += (size_t)B_ * H_;
  float* c      = ws + off; off += (size_t)B_ * H_;
  float* sel    = ws + off; off += (size_t)B_ * H_;
  float* tenc   = ws + off; off += (size_t)B_ * H_;
  float* hatt   = ws + off; off += (size_t)B_ * H_;        // also decoder h
  float* cdec   = ws + off; off += (size_t)B_ * H_;
  float* gates  = ws + off; off += (size_t)B_ * G4_;       // 8,388,608
  float* P      = ws + off; off += (size_t)B_ * B_;        // 16,777,216
  float* Vt     = ws + off; off += (size_t)H_ * B_;        // 2,097,152
  float* WoutT  = ws + off; off += (size_t)H_ * V_;        // 65,536
  int*   lens   = (int*)(ws + off); off += B_;

  const int BH = B_ * H_;

  lengths_k<<<dim3((B_ + 255) / 256), dim3(256), 0, stream>>>(text, lens);
  {
    int total = L_ * B_ * E_;
    stage_embs_k<<<dim3((total + 255) / 256), dim3(256), 0, stream>>>(text, emb, xs_enc, xs_dec);
  }
  // W_out [V,H] -> WoutT [H,V]
  transpose_k<<<dim3(H_ / 32, V_ / 32), dim3(256), 0, stream>>>(W_out, WoutT, V_, H_);

  // visual projection: v[b,h] = visual[b,:] . W_vis[h,:]
  gemm_nt_k<<<dim3(H_ / 64, B_ / 64), dim3(256), 0, stream>>>(
      visual, VIS_, W_vis, VIS_, VIS_,
      nullptr, 0, nullptr, 0, 0, nullptr, nullptr, v, H_, 0);

  // encoder LSTM
  fill_k<<<dim3((BH + 255) / 256), dim3(256), 0, stream>>>(h, 0.1f, BH);
  fill_k<<<dim3((BH + 255) / 256), dim3(256), 0, stream>>>(c, 0.1f, BH);
  for (int t = 0; t < L_; ++t) {
    gemm_nt_k<<<dim3(G4_ / 64, B_ / 64), dim3(256), 0, stream>>>(
        h, H_, W_hh, H_, H_,
        xs_enc + (size_t)t * B_ * E_, E_, W_ih, E_, E_,
        b_ih, b_hh, gates, G4_, 0);
    lstm_update_k<<<dim3((BH + 255) / 256), dim3(256), 0, stream>>>(
        gates, c, h, sel, lens, t);
  }

  // enc linear + relu
  gemm_nt_k<<<dim3(H_ / 64, B_ / 64), dim3(256), 0, stream>>>(
      sel, H_, W_enc, H_, H_,
      nullptr, 0, nullptr, 0, 0, b_enc, nullptr, tenc, H_, 1);

  // cosine attention
  rownorm_k<<<dim3(B_), dim3(256), 0, stream>>>(v, H_);
  rownorm_k<<<dim3(B_), dim3(256), 0, stream>>>(tenc, H_);
  // P[j,i] = t_j . v_i   (= sims^T, so softmax over axis 0 becomes row softmax)
  gemm_nt_k<<<dim3(B_ / 64, B_ / 64), dim3(256), 0, stream>>>(
      tenc, H_, v, H_, H_,
      nullptr, 0, nullptr, 0, 0, nullptr, nullptr, P, B_, 0);
  softmax_rows_k<<<dim3(B_), dim3(256), 0, stream>>>(P, B_);
  // Vt[h,i] = v[i,h]
  transpose_k<<<dim3(H_ / 32, B_ / 32), dim3(256), 0, stream>>>(v, Vt, B_, H_);
  // hatt[j,h] = sum_i P[j,i] v[i,h]
  gemm_nt_k<<<dim3(H_ / 64, B_ / 64), dim3(256), 0, stream>>>(
      P, B_, Vt, B_, B_,
      nullptr, 0, nullptr, 0, 0, nullptr, nullptr, hatt, H_, 0);
  rownorm_k<<<dim3(B_), dim3(256), 0, stream>>>(hatt, H_);

  // decoder LSTM: hs = cs = hatt
  copy_k<<<dim3((BH + 255) / 256), dim3(256), 0, stream>>>(cdec, hatt, BH);
  for (int t = 0; t < L_; ++t) {
    gemm_nt_k<<<dim3(G4_ / 64, B_ / 64), dim3(256), 0, stream>>>(
        hatt, H_, W_hh, H_, H_,
        xs_dec + (size_t)t * B_ * E_, E_, W_ih, E_, E_,
        b_ih, b_hh, gates, G4_, 0);
    lstm_update_k<<<dim3((BH + 255) / 256), dim3(256), 0, stream>>>(
        gates, cdec, hatt, nullptr, nullptr, t);
    dec_loss_k<<<dim3(B_), dim3(128), 0, stream>>>(hatt, WoutT, text, t, out);
  }
}

// Round 2
// 2213.493 us; speedup vs baseline: 2.9184x; 2.9184x over previous
//
#include <hip/hip_runtime.h>
#include <math.h>

#define B_    4096
#define L_    16
#define E_    50
#define EP_   64
#define H_    512
#define G4_   2048
#define V_    128
#define VIS_  2048

typedef unsigned short ushortT;
typedef ushortT ushort8 __attribute__((ext_vector_type(8)));
typedef short   short8  __attribute__((ext_vector_type(8)));
typedef float   f32x4   __attribute__((ext_vector_type(4)));

__device__ __forceinline__ ushortT f2bf(float f) {
  union { float f; unsigned u; } v; v.f = f;
  unsigned u = v.u;
  u += 0x7fffu + ((u >> 16) & 1u);
  return (ushortT)(u >> 16);
}
__device__ __forceinline__ float bf2f(ushortT h) {
  union { unsigned u; float f; } v; v.u = ((unsigned)h) << 16;
  return v.f;
}
static inline ushortT f2bf_h(float f) {
  union { float f; unsigned u; } v; v.f = f;
  unsigned u = v.u;
  u += 0x7fffu + ((u >> 16) & 1u);
  return (ushortT)(u >> 16);
}

__global__ void lengths_k(const int* __restrict__ text, int* __restrict__ lens) {
  int b = blockIdx.x * blockDim.x + threadIdx.x;
  if (b < B_) {
    int c = 0;
    for (int t = 0; t < L_; ++t) c += (text[b * L_ + t] != 0) ? 1 : 0;
    lens[b] = c;
  }
}

__global__ void stage_embs_k(const int* __restrict__ text, const float* __restrict__ emb,
                             ushortT* __restrict__ xs_enc, ushortT* __restrict__ xs_dec) {
  int idx = blockIdx.x * blockDim.x + threadIdx.x;
  const int total = L_ * B_ * EP_;
  if (idx >= total) return;
  int e = idx & 63;
  int r = idx >> 6;
  int b = r % B_;
  int t = r / B_;
  ushortT ve = 0, vd = 0;
  if (e < E_) {
    int id_enc = text[b * L_ + t];
    int id_dec = (t == 0) ? 0 : text[b * L_ + t - 1];
    ve = f2bf(emb[id_enc * E_ + e]);
    vd = f2bf(emb[id_dec * E_ + e]);
  }
  xs_enc[idx] = ve;
  xs_dec[idx] = vd;
}

__global__ void cvt_pad_k(const float* __restrict__ src, int scols,
                          ushortT* __restrict__ dst, int dcols, int rows) {
  int idx = blockIdx.x * blockDim.x + threadIdx.x;
  if (idx >= rows * dcols) return;
  int c = idx % dcols, r = idx / dcols;
  dst[idx] = (c < scols) ? f2bf(src[(size_t)r * scols + c]) : (ushortT)0;
}
__global__ void fill_bf_k(ushortT* __restrict__ p, ushortT v, int n) {
  int i = blockIdx.x * blockDim.x + threadIdx.x;
  if (i < n) p[i] = v;
}
__global__ void fill_f_k(float* __restrict__ p, float v, int n) {
  int i = blockIdx.x * blockDim.x + threadIdx.x;
  if (i < n) p[i] = v;
}
__global__ void copy_f_k(float* __restrict__ dst, const float* __restrict__ src, int n) {
  int i = blockIdx.x * blockDim.x + threadIdx.x;
  if (i < n) dst[i] = src[i];
}

// bf16 MFMA NT-GEMM: C[m,n] = A1[m,:].B1[n,:] (+A2[m,:].B2[n,:]) (+biases) (relu)
__global__ __launch_bounds__(256)
void gemm_bf16_k(const void* __restrict__ A1, int lda1, int K1, int a1f32,
                 const ushortT* __restrict__ B1, int ldb1,
                 const ushortT* __restrict__ A2, int lda2, int K2,
                 const ushortT* __restrict__ B2, int ldb2,
                 const float* __restrict__ bias1, const float* __restrict__ bias2,
                 float* __restrict__ Cf, ushortT* __restrict__ Cb, int ldc, int relu) {
  __shared__ ushortT As[128 * 32];
  __shared__ ushortT Bs[128 * 32];
  const int tid  = threadIdx.x;
  const int m0   = blockIdx.y * 128;
  const int n0   = blockIdx.x * 128;
  const int lane = tid & 63;
  const int wave = tid >> 6;
  const int wm   = (wave >> 1) * 64;
  const int wn   = (wave & 1) * 64;
  const int fr   = lane & 15;
  const int kq   = (lane >> 4) * 8;

  f32x4 acc[4][4];
#pragma unroll
  for (int i = 0; i < 4; ++i)
#pragma unroll
    for (int j = 0; j < 4; ++j)
#pragma unroll
      for (int r = 0; r < 4; ++r) acc[i][j][r] = 0.f;

  auto run_seg = [&](const void* A, int lda, int K, int af32,
                     const ushortT* __restrict__ Bp, int ldb) {
    for (int k0 = 0; k0 < K; k0 += 32) {
#pragma unroll
      for (int l = 0; l < 2; ++l) {
        int e = tid + l * 256;
        int r = e >> 2, cc = (e & 3) * 8;
        ushort8 av;
        if (af32) {
          const float* ap = (const float*)A + (size_t)(m0 + r) * lda + k0 + cc;
#pragma unroll
          for (int q = 0; q < 8; ++q) av[q] = f2bf(ap[q]);
        } else {
          av = *(const ushort8*)((const ushortT*)A + (size_t)(m0 + r) * lda + k0 + cc);
        }
        *(ushort8*)(&As[r * 32 + cc]) = av;
        ushort8 bv = *(const ushort8*)(Bp + (size_t)(n0 + r) * ldb + k0 + cc);
        *(ushort8*)(&Bs[r * 32 + cc]) = bv;
      }
      __syncthreads();
      short8 afr[4], bfr[4];
#pragma unroll
      for (int mi = 0; mi < 4; ++mi)
        afr[mi] = *(const short8*)(&As[(wm + mi * 16 + fr) * 32 + kq]);
#pragma unroll
      for (int ni = 0; ni < 4; ++ni)
        bfr[ni] = *(const short8*)(&Bs[(wn + ni * 16 + fr) * 32 + kq]);
#pragma unroll
      for (int mi = 0; mi < 4; ++mi)
#pragma unroll
        for (int ni = 0; ni < 4; ++ni)
          acc[mi][ni] = __builtin_amdgcn_mfma_f32_16x16x32_bf16(afr[mi], bfr[ni], acc[mi][ni], 0, 0, 0);
      __syncthreads();
    }
  };
  run_seg(A1, lda1, K1, a1f32, B1, ldb1);
  if (A2) run_seg(A2, lda2, K2, 0, B2, ldb2);

#pragma unroll
  for (int mi = 0; mi < 4; ++mi) {
#pragma unroll
    for (int r = 0; r < 4; ++r) {
      int m = m0 + wm + mi * 16 + (lane >> 4) * 4 + r;
#pragma unroll
      for (int ni = 0; ni < 4; ++ni) {
        int n = n0 + wn + ni * 16 + (lane & 15);
        float vv = acc[mi][ni][r];
        if (bias1) vv += bias1[n];
        if (bias2) vv += bias2[n];
        if (relu) vv = fmaxf(vv, 0.f);
        if (Cf) Cf[(size_t)m * ldc + n] = vv;
        if (Cb) Cb[(size_t)m * ldc + n] = f2bf(vv);
      }
    }
  }
}

__global__ void lstm_update_k(const ushortT* __restrict__ gates, float* __restrict__ c,
                              ushortT* __restrict__ hbf, ushortT* __restrict__ selbf,
                              const int* __restrict__ lens, int t) {
  int idx = blockIdx.x * blockDim.x + threadIdx.x;
  if (idx >= B_ * H_) return;
  int b = idx >> 9;
  int j = idx & (H_ - 1);
  const ushortT* g = gates + (size_t)b * G4_;
  float ig = bf2f(g[j]), fg = bf2f(g[H_ + j]), gg = bf2f(g[2 * H_ + j]), og = bf2f(g[3 * H_ + j]);
  float si = 1.f / (1.f + expf(-ig));
  float sf = 1.f / (1.f + expf(-fg));
  float so = 1.f / (1.f + expf(-og));
  float tg = tanhf(gg);
  float cn = sf * c[idx] + si * tg;
  float hn = so * tanhf(cn);
  c[idx] = cn;
  hbf[idx] = f2bf(hn);
  if (selbf) {
    int len = lens[b];
    int eff = (len == 0) ? L_ : len;
    if (t == eff - 1) selbf[idx] = f2bf(hn);
  }
}

__global__ void rownorm_bf_k(ushortT* __restrict__ x, int n) {
  int b = blockIdx.x, tid = threadIdx.x;
  ushortT* row = x + (size_t)b * n;
  float s = 0.f;
  for (int i = tid; i < n; i += 256) { float v = bf2f(row[i]); s += v * v; }
  __shared__ float red[256];
  red[tid] = s; __syncthreads();
  for (int st = 128; st > 0; st >>= 1) { if (tid < st) red[tid] += red[tid + st]; __syncthreads(); }
  float inv = 1.f / sqrtf(red[0]);
  for (int i = tid; i < n; i += 256) row[i] = f2bf(bf2f(row[i]) * inv);
}

__global__ void rownorm_fb_k(float* __restrict__ x, ushortT* __restrict__ xb, int n) {
  int b = blockIdx.x, tid = threadIdx.x;
  float* row = x + (size_t)b * n;
  float s = 0.f;
  for (int i = tid; i < n; i += 256) { float v = row[i]; s += v * v; }
  __shared__ float red[256];
  red[tid] = s; __syncthreads();
  for (int st = 128; st > 0; st >>= 1) { if (tid < st) red[tid] += red[tid + st]; __syncthreads(); }
  float inv = 1.f / sqrtf(red[0]);
  for (int i = tid; i < n; i += 256) {
    float v = row[i] * inv;
    row[i] = v;
    xb[(size_t)b * n + i] = f2bf(v);
  }
}

__global__ __launch_bounds__(256)
void softmax_bf_rows_k(ushortT* __restrict__ P) {
  int r = blockIdx.x, tid = threadIdx.x;
  ushortT* row = P + (size_t)r * B_;
  float xv[16];
  float m = -1e30f;
#pragma unroll
  for (int l = 0; l < 16; ++l) { float v = bf2f(row[tid + l * 256]); xv[l] = v; m = fmaxf(m, v); }
  __shared__ float red[256];
  red[tid] = m; __syncthreads();
  for (int st = 128; st > 0; st >>= 1) { if (tid < st) red[tid] = fmaxf(red[tid], red[tid + st]); __syncthreads(); }
  m = red[0]; __syncthreads();
  float s = 0.f;
#pragma unroll
  for (int l = 0; l < 16; ++l) { float e = expf(xv[l] - m); xv[l] = e; s += e; }
  red[tid] = s; __syncthreads();
  for (int st = 128; st > 0; st >>= 1) { if (tid < st) red[tid] += red[tid + st]; __syncthreads(); }
  float inv = 1.f / red[0];
#pragma unroll
  for (int l = 0; l < 16; ++l) row[tid + l * 256] = f2bf(xv[l] * inv);
}

__global__ void transpose_bf_k(const ushortT* __restrict__ in, ushortT* __restrict__ out,
                               int R, int Ccols) {
  __shared__ ushortT tile[32][33];
  int c0 = blockIdx.x * 32, r0 = blockIdx.y * 32;
  int tx = threadIdx.x & 31, ty = threadIdx.x >> 5;
  for (int i = ty; i < 32; i += 8) tile[i][tx] = in[(size_t)(r0 + i) * Ccols + c0 + tx];
  __syncthreads();
  for (int i = ty; i < 32; i += 8) out[(size_t)(c0 + i) * R + r0 + tx] = tile[tx][i];
}

__global__ __launch_bounds__(256)
void dec_loss_k(const float* __restrict__ logits, const int* __restrict__ text,
                int t, float* __restrict__ out) {
  int wave = threadIdx.x >> 6, lane = threadIdx.x & 63;
  int b = blockIdx.x * 4 + wave;
  const float* row = logits + (size_t)b * V_;
  float2 x = *(const float2*)(row + lane * 2);
  float mx = fmaxf(x.x, x.y);
#pragma unroll
  for (int m = 32; m > 0; m >>= 1) mx = fmaxf(mx, __shfl_xor(mx, m));
  float s = expf(x.x - mx) + expf(x.y - mx);
#pragma unroll
  for (int m = 32; m > 0; m >>= 1) s += __shfl_xor(s, m);
  if (lane == 0) {
    int tgt = text[b * L_ + t];
    float loss = (mx + logf(s) - row[tgt]) * (1.f / (float)L_);
    if (t == 0) out[b] = loss;
    else out[b] += loss;
  }
}

extern "C" void kernel_launch(void* const* d_in, const int* in_sizes, int n_in,
                              void* d_out, int out_size, void* d_ws, size_t ws_size,
                              hipStream_t stream) {
  const float* visual = (const float*)d_in[0];
  const int*   text   = (const int*)  d_in[1];
  const float* emb    = (const float*)d_in[2];
  const float* W_ih   = (const float*)d_in[3];
  const float* W_hh   = (const float*)d_in[4];
  const float* b_ih   = (const float*)d_in[5];
  const float* b_hh   = (const float*)d_in[6];
  const float* W_enc  = (const float*)d_in[7];
  const float* b_enc  = (const float*)d_in[8];
  const float* W_out  = (const float*)d_in[9];
  const float* W_vis  = (const float*)d_in[10];
  float* out = (float*)d_out;

  char* w = (char*)d_ws;
  auto alloc = [&](size_t bytes) { char* p = w; w += (bytes + 255) & ~(size_t)255; return p; };
  ushortT* xs_enc = (ushortT*)alloc((size_t)L_ * B_ * EP_ * 2);
  ushortT* xs_dec = (ushortT*)alloc((size_t)L_ * B_ * EP_ * 2);
  ushortT* Whhbf  = (ushortT*)alloc((size_t)G4_ * H_ * 2);
  ushortT* Wihbf  = (ushortT*)alloc((size_t)G4_ * EP_ * 2);
  ushortT* Wvisbf = (ushortT*)alloc((size_t)H_ * VIS_ * 2);
  ushortT* Wencbf = (ushortT*)alloc((size_t)H_ * H_ * 2);
  ushortT* Woutbf = (ushortT*)alloc((size_t)V_ * H_ * 2);
  ushortT* hencbf = (ushortT*)alloc((size_t)B_ * H_ * 2);
  float*   cenc   = (float*)  alloc((size_t)B_ * H_ * 4);
  ushortT* selbf  = (ushortT*)alloc((size_t)B_ * H_ * 2);
  ushortT* vbf    = (ushortT*)alloc((size_t)B_ * H_ * 2);
  ushortT* tencbf = (ushortT*)alloc((size_t)B_ * H_ * 2);
  ushortT* Pbf    = (ushortT*)alloc((size_t)B_ * B_ * 2);
  ushortT* Vtbf   = (ushortT*)alloc((size_t)H_ * B_ * 2);
  float*   hatt   = (float*)  alloc((size_t)B_ * H_ * 4);
  float*   cdec   = (float*)  alloc((size_t)B_ * H_ * 4);
  ushortT* hdecbf = (ushortT*)alloc((size_t)B_ * H_ * 2);
  ushortT* gates  = (ushortT*)alloc((size_t)B_ * G4_ * 2);
  float*   logits = (float*)  alloc((size_t)B_ * V_ * 4);
  int*     lens   = (int*)    alloc((size_t)B_ * 4);

  const int BH = B_ * H_;

  lengths_k<<<dim3((B_ + 255) / 256), dim3(256), 0, stream>>>(text, lens);
  stage_embs_k<<<dim3((L_ * B_ * EP_) / 256), dim3(256), 0, stream>>>(text, emb, xs_enc, xs_dec);

  cvt_pad_k<<<dim3((G4_ * H_) / 256),  dim3(256), 0, stream>>>(W_hh,  H_,   Whhbf,  H_,   G4_);
  cvt_pad_k<<<dim3((G4_ * EP_) / 256), dim3(256), 0, stream>>>(W_ih,  E_,   Wihbf,  EP_,  G4_);
  cvt_pad_k<<<dim3((H_ * VIS_) / 256), dim3(256), 0, stream>>>(W_vis, VIS_, Wvisbf, VIS_, H_);
  cvt_pad_k<<<dim3((H_ * H_) / 256),   dim3(256), 0, stream>>>(W_enc, H_,   Wencbf, H_,   H_);
  cvt_pad_k<<<dim3((V_ * H_) / 256),   dim3(256), 0, stream>>>(W_out, H_,   Woutbf, H_,   V_);

  gemm_bf16_k<<<dim3(H_ / 128, B_ / 128), dim3(256), 0, stream>>>(
      visual, VIS_, VIS_, 1, Wvisbf, VIS_,
      nullptr, 0, 0, nullptr, 0,
      nullptr, nullptr, nullptr, vbf, H_, 0);

  fill_bf_k<<<dim3(BH / 256), dim3(256), 0, stream>>>(hencbf, f2bf_h(0.1f), BH);
  fill_f_k<<<dim3(BH / 256), dim3(256), 0, stream>>>(cenc, 0.1f, BH);
  for (int t = 0; t < L_; ++t) {
    gemm_bf16_k<<<dim3(G4_ / 128, B_ / 128), dim3(256), 0, stream>>>(
        hencbf, H_, H_, 0, Whhbf, H_,
        xs_enc + (size_t)t * B_ * EP_, EP_, EP_, Wihbf, EP_,
        b_ih, b_hh, nullptr, gates, G4_, 0);
    lstm_update_k<<<dim3(BH / 256), dim3(256), 0, stream>>>(gates, cenc, hencbf, selbf, lens, t);
  }

  gemm_bf16_k<<<dim3(H_ / 128, B_ / 128), dim3(256), 0, stream>>>(
      selbf, H_, H_, 0, Wencbf, H_,
      nullptr, 0, 0, nullptr, 0,
      b_enc, nullptr, nullptr, tencbf, H_, 1);

  rownorm_bf_k<<<dim3(B_), dim3(256), 0, stream>>>(vbf, H_);
  rownorm_bf_k<<<dim3(B_), dim3(256), 0, stream>>>(tencbf, H_);
  gemm_bf16_k<<<dim3(B_ / 128, B_ / 128), dim3(256), 0, stream>>>(
      tencbf, H_, H_, 0, vbf, H_,
      nullptr, 0, 0, nullptr, 0,
      nullptr, nullptr, nullptr, Pbf, B_, 0);
  softmax_bf_rows_k<<<dim3(B_), dim3(256), 0, stream>>>(Pbf);
  transpose_bf_k<<<dim3(H_ / 32, B_ / 32), dim3(256), 0, stream>>>(vbf, Vtbf, B_, H_);
  gemm_bf16_k<<<dim3(H_ / 128, B_ / 128), dim3(256), 0, stream>>>(
      Pbf, B_, B_, 0, Vtbf, B_,
      nullptr, 0, 0, nullptr, 0,
      nullptr, nullptr, hatt, nullptr, H_, 0);
  rownorm_fb_k<<<dim3(B_), dim3(256), 0, stream>>>(hatt, hdecbf, H_);
  copy_f_k<<<dim3(BH / 256), dim3(256), 0, stream>>>(cdec, hatt, BH);

  for (int t = 0; t < L_; ++t) {
    gemm_bf16_k<<<dim3(G4_ / 128, B_ / 128), dim3(256), 0, stream>>>(
        hdecbf, H_, H_, 0, Whhbf, H_,
        xs_dec + (size_t)t * B_ * EP_, EP_, EP_, Wihbf, EP_,
        b_ih, b_hh, nullptr, gates, G4_, 0);
    lstm_update_k<<<dim3(BH / 256), dim3(256), 0, stream>>>(gates, cdec, hdecbf, nullptr, nullptr, t);
    gemm_bf16_k<<<dim3(V_ / 128, B_ / 128), dim3(256), 0, stream>>>(
        hdecbf, H_, H_, 0, Woutbf, H_,
        nullptr, 0, 0, nullptr, 0,
        nullptr, nullptr, logits, nullptr, V_, 0);
    dec_loss_k<<<dim3(B_ / 4), dim3(256), 0, stream>>>(logits, text, t, out);
  }
}

// Round 3
// 1538.290 us; speedup vs baseline: 4.1994x; 1.4389x over previous
//
#include <hip/hip_runtime.h>
#include <math.h>

#define B_    4096
#define L_    16
#define E_    50
#define EP_   64
#define H_    512
#define G4_   2048
#define V_    128
#define VIS_  2048

typedef unsigned short ushortT;
typedef ushortT ushort8 __attribute__((ext_vector_type(8)));
typedef ushortT ushort4v __attribute__((ext_vector_type(4)));
typedef short   short8  __attribute__((ext_vector_type(8)));
typedef float   f32x4   __attribute__((ext_vector_type(4)));

__device__ __forceinline__ ushortT f2bf(float f) {
  union { float f; unsigned u; } v; v.f = f;
  unsigned u = v.u;
  u += 0x7fffu + ((u >> 16) & 1u);
  return (ushortT)(u >> 16);
}
__device__ __forceinline__ float bf2f(ushortT h) {
  union { unsigned u; float f; } v; v.u = ((unsigned)h) << 16;
  return v.f;
}
static inline ushortT f2bf_h(float f) {
  union { float f; unsigned u; } v; v.f = f;
  unsigned u = v.u;
  u += 0x7fffu + ((u >> 16) & 1u);
  return (ushortT)(u >> 16);
}

// ---------------------------------------------------------------- prep
__global__ void lengths_k(const int* __restrict__ text, int* __restrict__ lens) {
  int b = blockIdx.x * blockDim.x + threadIdx.x;
  if (b < B_) {
    int c = 0;
    for (int t = 0; t < L_; ++t) c += (text[b * L_ + t] != 0) ? 1 : 0;
    lens[b] = c;
  }
}

__global__ void stage_embs_k(const int* __restrict__ text, const float* __restrict__ emb,
                             ushortT* __restrict__ xs_enc, ushortT* __restrict__ xs_dec) {
  int idx = blockIdx.x * blockDim.x + threadIdx.x;
  const int total = L_ * B_ * EP_;
  if (idx >= total) return;
  int e = idx & 63;
  int r = idx >> 6;
  int b = r % B_;
  int t = r / B_;
  ushortT ve = 0, vd = 0;
  if (e < E_) {
    int id_enc = text[b * L_ + t];
    int id_dec = (t == 0) ? 0 : text[b * L_ + t - 1];
    ve = f2bf(emb[id_enc * E_ + e]);
    vd = f2bf(emb[id_dec * E_ + e]);
  }
  xs_enc[idx] = ve;
  xs_dec[idx] = vd;
}

// gate-interleaved: new row p = 4*j + q  <-  old row q*H + j  (q: i,f,g,o)
__global__ void prep_whh_k(const float* __restrict__ W, ushortT* __restrict__ D) {
  int idx = blockIdx.x * 256 + threadIdx.x;       // G4_*H_
  if (idx >= G4_ * H_) return;
  int k = idx & (H_ - 1), p = idx >> 9;
  int j = p >> 2, q = p & 3;
  D[idx] = f2bf(W[(size_t)(q * H_ + j) * H_ + k]);
}
__global__ void prep_wih_k(const float* __restrict__ W, ushortT* __restrict__ D) {
  int idx = blockIdx.x * 256 + threadIdx.x;       // G4_*EP_
  if (idx >= G4_ * EP_) return;
  int k = idx & 63, p = idx >> 6;
  int j = p >> 2, q = p & 3;
  D[idx] = (k < E_) ? f2bf(W[(size_t)(q * H_ + j) * E_ + k]) : (ushortT)0;
}
__global__ void prep_bias_k(const float* __restrict__ bi, const float* __restrict__ bh,
                            float* __restrict__ D) {
  int p = blockIdx.x * 256 + threadIdx.x;
  if (p >= G4_) return;
  int j = p >> 2, q = p & 3;
  int o = q * H_ + j;
  D[p] = bi[o] + bh[o];
}
__global__ void cvt_k(const float* __restrict__ s, ushortT* __restrict__ d, int n) {
  int i = blockIdx.x * 256 + threadIdx.x;
  if (i < n) d[i] = f2bf(s[i]);
}
__global__ void cvt4_k(const float* __restrict__ s, ushortT* __restrict__ d, int n4) {
  int i = blockIdx.x * 256 + threadIdx.x;
  if (i >= n4) return;
  float4 v = ((const float4*)s)[i];
  ushort4v o;
  o[0] = f2bf(v.x); o[1] = f2bf(v.y); o[2] = f2bf(v.z); o[3] = f2bf(v.w);
  ((ushort4v*)d)[i] = o;
}
__global__ void fill_bf_k(ushortT* __restrict__ p, ushortT v, int n) {
  int i = blockIdx.x * blockDim.x + threadIdx.x;
  if (i < n) p[i] = v;
}
__global__ void fill_f_k(float* __restrict__ p, float v, int n) {
  int i = blockIdx.x * blockDim.x + threadIdx.x;
  if (i < n) p[i] = v;
}

// ---------------------------------------------------------------- generic bf16 MFMA NT-GEMM
// C[m,n] = A[m,:].B[n,:] (+bias) (relu). 128x128 tile, BK=64, padded LDS (stride 72).
__global__ __launch_bounds__(256)
void gemm_bf16_k(const ushortT* __restrict__ A, int lda, int K,
                 const ushortT* __restrict__ B, int ldb,
                 const float* __restrict__ bias,
                 float* __restrict__ Cf, ushortT* __restrict__ Cb, int ldc, int relu) {
  __shared__ ushortT As[128 * 72];
  __shared__ ushortT Bs[128 * 72];
  const int tid = threadIdx.x;
  const int m0 = blockIdx.y * 128, n0 = blockIdx.x * 128;
  const int lane = tid & 63, wave = tid >> 6;
  const int wm = (wave >> 1) * 64, wn = (wave & 1) * 64;
  const int fr = lane & 15, kq = (lane >> 4) * 8;

  f32x4 acc[4][4];
#pragma unroll
  for (int i = 0; i < 4; ++i)
#pragma unroll
    for (int j = 0; j < 4; ++j)
#pragma unroll
      for (int r = 0; r < 4; ++r) acc[i][j][r] = 0.f;

  for (int k0 = 0; k0 < K; k0 += 64) {
#pragma unroll
    for (int l = 0; l < 4; ++l) {
      int e = tid + l * 256;
      int r = e >> 3, cc = (e & 7) * 8;
      *(ushort8*)(&As[r * 72 + cc]) = *(const ushort8*)(&A[(size_t)(m0 + r) * lda + k0 + cc]);
      *(ushort8*)(&Bs[r * 72 + cc]) = *(const ushort8*)(&B[(size_t)(n0 + r) * ldb + k0 + cc]);
    }
    __syncthreads();
#pragma unroll
    for (int kk = 0; kk < 2; ++kk) {
      short8 afr[4], bfr[4];
#pragma unroll
      for (int mi = 0; mi < 4; ++mi)
        afr[mi] = *(const short8*)(&As[(wm + mi * 16 + fr) * 72 + kk * 32 + kq]);
#pragma unroll
      for (int ni = 0; ni < 4; ++ni)
        bfr[ni] = *(const short8*)(&Bs[(wn + ni * 16 + fr) * 72 + kk * 32 + kq]);
#pragma unroll
      for (int mi = 0; mi < 4; ++mi)
#pragma unroll
        for (int ni = 0; ni < 4; ++ni)
          acc[mi][ni] = __builtin_amdgcn_mfma_f32_16x16x32_bf16(afr[mi], bfr[ni], acc[mi][ni], 0, 0, 0);
    }
    __syncthreads();
  }

#pragma unroll
  for (int mi = 0; mi < 4; ++mi) {
#pragma unroll
    for (int r = 0; r < 4; ++r) {
      int m = m0 + wm + mi * 16 + (lane >> 4) * 4 + r;
#pragma unroll
      for (int ni = 0; ni < 4; ++ni) {
        int n = n0 + wn + ni * 16 + fr;
        float vv = acc[mi][ni][r];
        if (bias) vv += bias[n];
        if (relu) vv = fmaxf(vv, 0.f);
        if (Cf) Cf[(size_t)m * ldc + n] = vv;
        if (Cb) Cb[(size_t)m * ldc + n] = f2bf(vv);
      }
    }
  }
}

// ---------------------------------------------------------------- fused LSTM step
// gates = hin.Whh^T + xs.Wih^T + biasc (gate-interleaved N), then cell update in epilogue.
__global__ __launch_bounds__(256)
void lstm_gemm_k(const ushortT* __restrict__ hin, const ushortT* __restrict__ Whh,
                 const ushortT* __restrict__ xs,  const ushortT* __restrict__ Wih,
                 const float* __restrict__ biasc,
                 float* __restrict__ c, ushortT* __restrict__ hout,
                 ushortT* __restrict__ sel, const int* __restrict__ lens, int t) {
  __shared__ char smem[2 * 128 * 72 * 2];       // 36864 B
  ushortT* As = (ushortT*)smem;
  ushortT* Bs = As + 128 * 72;
  float*   gb = (float*)smem;                    // 64 x 132 fp32 overlay (33792 B)

  const int tid = threadIdx.x;
  const int m0 = blockIdx.y * 128, n0 = blockIdx.x * 128;
  const int lane = tid & 63, wave = tid >> 6;
  const int wm = (wave >> 1) * 64, wn = (wave & 1) * 64;
  const int fr = lane & 15, kq = (lane >> 4) * 8;

  f32x4 acc[4][4];
#pragma unroll
  for (int i = 0; i < 4; ++i)
#pragma unroll
    for (int j = 0; j < 4; ++j)
#pragma unroll
      for (int r = 0; r < 4; ++r) acc[i][j][r] = 0.f;

  for (int it = 0; it < 9; ++it) {
    const ushortT* Ab; const ushortT* Bb; int ldx, k0;
    if (it < 8) { Ab = hin; Bb = Whh; ldx = H_;  k0 = it * 64; }
    else        { Ab = xs;  Bb = Wih; ldx = EP_; k0 = 0; }
#pragma unroll
    for (int l = 0; l < 4; ++l) {
      int e = tid + l * 256;
      int r = e >> 3, cc = (e & 7) * 8;
      *(ushort8*)(&As[r * 72 + cc]) = *(const ushort8*)(&Ab[(size_t)(m0 + r) * ldx + k0 + cc]);
      *(ushort8*)(&Bs[r * 72 + cc]) = *(const ushort8*)(&Bb[(size_t)(n0 + r) * ldx + k0 + cc]);
    }
    __syncthreads();
#pragma unroll
    for (int kk = 0; kk < 2; ++kk) {
      short8 afr[4], bfr[4];
#pragma unroll
      for (int mi = 0; mi < 4; ++mi)
        afr[mi] = *(const short8*)(&As[(wm + mi * 16 + fr) * 72 + kk * 32 + kq]);
#pragma unroll
      for (int ni = 0; ni < 4; ++ni)
        bfr[ni] = *(const short8*)(&Bs[(wn + ni * 16 + fr) * 72 + kk * 32 + kq]);
#pragma unroll
      for (int mi = 0; mi < 4; ++mi)
#pragma unroll
        for (int ni = 0; ni < 4; ++ni)
          acc[mi][ni] = __builtin_amdgcn_mfma_f32_16x16x32_bf16(afr[mi], bfr[ni], acc[mi][ni], 0, 0, 0);
    }
    __syncthreads();
  }

  // epilogue: two half-tile passes through fp32 LDS gate buffer
  const int jg0 = blockIdx.x * 32;
  for (int pass = 0; pass < 2; ++pass) {
    if ((wave >> 1) == pass) {
#pragma unroll
      for (int mi = 0; mi < 4; ++mi) {
        int rowb = mi * 16 + (lane >> 4) * 4;
#pragma unroll
        for (int r = 0; r < 4; ++r)
#pragma unroll
          for (int ni = 0; ni < 4; ++ni)
            gb[(rowb + r) * 132 + wn + ni * 16 + fr] = acc[mi][ni][r];
      }
    }
    __syncthreads();
#pragma unroll
    for (int p = 0; p < 8; ++p) {
      int idx = p * 256 + tid;
      int mrow = idx >> 5, jl = idx & 31;
      f32x4 g = *(const f32x4*)(&gb[mrow * 132 + jl * 4]);
      f32x4 bb = *(const f32x4*)(&biasc[(jg0 + jl) * 4]);
      int brow = m0 + pass * 64 + mrow;
      int jg = jg0 + jl;
      size_t ci = (size_t)brow * H_ + jg;
      float ig = g[0] + bb[0], fg = g[1] + bb[1], gg = g[2] + bb[2], og = g[3] + bb[3];
      float si = 1.f / (1.f + expf(-ig));
      float sf = 1.f / (1.f + expf(-fg));
      float so = 1.f / (1.f + expf(-og));
      float cn = sf * c[ci] + si * tanhf(gg);
      float hn = so * tanhf(cn);
      c[ci] = cn;
      hout[ci] = f2bf(hn);
      if (sel) {
        int len = lens[brow];
        int eff = (len == 0) ? L_ : len;
        if (t == eff - 1) sel[ci] = f2bf(hn);
      }
    }
    __syncthreads();
  }
}

// ---------------------------------------------------------------- fused decoder logits+NLL
// logits = h.Wout^T [128-tile x V=128], log-softmax per row, out[b] (+)= loss/L
__global__ __launch_bounds__(256)
void dec_loss_gemm_k(const ushortT* __restrict__ h, const ushortT* __restrict__ Wout,
                     const int* __restrict__ text, int t, float* __restrict__ out) {
  __shared__ ushortT As[128 * 72];
  __shared__ ushortT Bs[128 * 72];
  __shared__ float lsmax[2][128];
  __shared__ float lssum[2][128];
  const int tid = threadIdx.x;
  const int m0 = blockIdx.x * 128;
  const int lane = tid & 63, wave = tid >> 6;
  const int wm = (wave >> 1) * 64, wn = (wave & 1) * 64;
  const int fr = lane & 15, kq = (lane >> 4) * 8;

  f32x4 acc[4][4];
#pragma unroll
  for (int i = 0; i < 4; ++i)
#pragma unroll
    for (int j = 0; j < 4; ++j)
#pragma unroll
      for (int r = 0; r < 4; ++r) acc[i][j][r] = 0.f;

  for (int k0 = 0; k0 < H_; k0 += 64) {
#pragma unroll
    for (int l = 0; l < 4; ++l) {
      int e = tid + l * 256;
      int r = e >> 3, cc = (e & 7) * 8;
      *(ushort8*)(&As[r * 72 + cc]) = *(const ushort8*)(&h[(size_t)(m0 + r) * H_ + k0 + cc]);
      *(ushort8*)(&Bs[r * 72 + cc]) = *(const ushort8*)(&Wout[(size_t)r * H_ + k0 + cc]);
    }
    __syncthreads();
#pragma unroll
    for (int kk = 0; kk < 2; ++kk) {
      short8 afr[4], bfr[4];
#pragma unroll
      for (int mi = 0; mi < 4; ++mi)
        afr[mi] = *(const short8*)(&As[(wm + mi * 16 + fr) * 72 + kk * 32 + kq]);
#pragma unroll
      for (int ni = 0; ni < 4; ++ni)
        bfr[ni] = *(const short8*)(&Bs[(wn + ni * 16 + fr) * 72 + kk * 32 + kq]);
#pragma unroll
      for (int mi = 0; mi < 4; ++mi)
#pragma unroll
        for (int ni = 0; ni < 4; ++ni)
          acc[mi][ni] = __builtin_amdgcn_mfma_f32_16x16x32_bf16(afr[mi], bfr[ni], acc[mi][ni], 0, 0, 0);
    }
    __syncthreads();
  }

  const int half = wn >> 6;
#pragma unroll
  for (int mi = 0; mi < 4; ++mi)
#pragma unroll
    for (int r = 0; r < 4; ++r) {
      float mx = acc[mi][0][r];
#pragma unroll
      for (int ni = 1; ni < 4; ++ni) mx = fmaxf(mx, acc[mi][ni][r]);
#pragma unroll
      for (int d = 1; d < 16; d <<= 1) mx = fmaxf(mx, __shfl_xor(mx, d));
      int mloc = wm + mi * 16 + (lane >> 4) * 4 + r;
      if (fr == 0) lsmax[half][mloc] = mx;
    }
  __syncthreads();
#pragma unroll
  for (int mi = 0; mi < 4; ++mi)
#pragma unroll
    for (int r = 0; r < 4; ++r) {
      int mloc = wm + mi * 16 + (lane >> 4) * 4 + r;
      float M = fmaxf(lsmax[0][mloc], lsmax[1][mloc]);
      float s = 0.f;
#pragma unroll
      for (int ni = 0; ni < 4; ++ni) s += expf(acc[mi][ni][r] - M);
#pragma unroll
      for (int d = 1; d < 16; d <<= 1) s += __shfl_xor(s, d);
      if (fr == 0) lssum[half][mloc] = s;
    }
  __syncthreads();
#pragma unroll
  for (int mi = 0; mi < 4; ++mi)
#pragma unroll
    for (int r = 0; r < 4; ++r) {
      int mloc = wm + mi * 16 + (lane >> 4) * 4 + r;
      float M = fmaxf(lsmax[0][mloc], lsmax[1][mloc]);
      float lse = M + logf(lssum[0][mloc] + lssum[1][mloc]);
      int b = m0 + mloc;
      int tgt = text[b * L_ + t];
#pragma unroll
      for (int ni = 0; ni < 4; ++ni) {
        int colg = wn + ni * 16 + fr;
        if (colg == tgt) {
          float loss = (lse - acc[mi][ni][r]) * (1.f / (float)L_);
          if (t == 0) out[b] = loss;
          else out[b] += loss;
        }
      }
    }
}

// ---------------------------------------------------------------- norms / softmax / transpose
__global__ void rownorm_bf_k(ushortT* __restrict__ x, int n) {
  int b = blockIdx.x, tid = threadIdx.x;
  ushortT* row = x + (size_t)b * n;
  float s = 0.f;
  for (int i = tid; i < n; i += 256) { float v = bf2f(row[i]); s += v * v; }
  __shared__ float red[256];
  red[tid] = s; __syncthreads();
  for (int st = 128; st > 0; st >>= 1) { if (tid < st) red[tid] += red[tid + st]; __syncthreads(); }
  float inv = 1.f / sqrtf(red[0]);
  for (int i = tid; i < n; i += 256) row[i] = f2bf(bf2f(row[i]) * inv);
}

// normalize fp32 row -> write bf16 h0 and fp32 c0 for decoder
__global__ void rownorm_fcb_k(const float* __restrict__ x, ushortT* __restrict__ xb,
                              float* __restrict__ c2, int n) {
  int b = blockIdx.x, tid = threadIdx.x;
  const float* row = x + (size_t)b * n;
  float s = 0.f;
  for (int i = tid; i < n; i += 256) { float v = row[i]; s += v * v; }
  __shared__ float red[256];
  red[tid] = s; __syncthreads();
  for (int st = 128; st > 0; st >>= 1) { if (tid < st) red[tid] += red[tid + st]; __syncthreads(); }
  float inv = 1.f / sqrtf(red[0]);
  for (int i = tid; i < n; i += 256) {
    float v = row[i] * inv;
    xb[(size_t)b * n + i] = f2bf(v);
    c2[(size_t)b * n + i] = v;
  }
}

__global__ __launch_bounds__(256)
void softmax_bf_rows_k(ushortT* __restrict__ P) {
  int r = blockIdx.x, tid = threadIdx.x;
  ushortT* row = P + (size_t)r * B_;
  float xv[16];
  float m = -1e30f;
#pragma unroll
  for (int l = 0; l < 16; ++l) { float v = bf2f(row[tid + l * 256]); xv[l] = v; m = fmaxf(m, v); }
  __shared__ float red[256];
  red[tid] = m; __syncthreads();
  for (int st = 128; st > 0; st >>= 1) { if (tid < st) red[tid] = fmaxf(red[tid], red[tid + st]); __syncthreads(); }
  m = red[0]; __syncthreads();
  float s = 0.f;
#pragma unroll
  for (int l = 0; l < 16; ++l) { float e = expf(xv[l] - m); xv[l] = e; s += e; }
  red[tid] = s; __syncthreads();
  for (int st = 128; st > 0; st >>= 1) { if (tid < st) red[tid] += red[tid + st]; __syncthreads(); }
  float inv = 1.f / red[0];
#pragma unroll
  for (int l = 0; l < 16; ++l) row[tid + l * 256] = f2bf(xv[l] * inv);
}

__global__ void transpose_bf_k(const ushortT* __restrict__ in, ushortT* __restrict__ out,
                               int R, int Ccols) {
  __shared__ ushortT tile[32][33];
  int c0 = blockIdx.x * 32, r0 = blockIdx.y * 32;
  int tx = threadIdx.x & 31, ty = threadIdx.x >> 5;
  for (int i = ty; i < 32; i += 8) tile[i][tx] = in[(size_t)(r0 + i) * Ccols + c0 + tx];
  __syncthreads();
  for (int i = ty; i < 32; i += 8) out[(size_t)(c0 + i) * R + r0 + tx] = tile[tx][i];
}

// ================================================================ launch
extern "C" void kernel_launch(void* const* d_in, const int* in_sizes, int n_in,
                              void* d_out, int out_size, void* d_ws, size_t ws_size,
                              hipStream_t stream) {
  const float* visual = (const float*)d_in[0];
  const int*   text   = (const int*)  d_in[1];
  const float* emb    = (const float*)d_in[2];
  const float* W_ih   = (const float*)d_in[3];
  const float* W_hh   = (const float*)d_in[4];
  const float* b_ih   = (const float*)d_in[5];
  const float* b_hh   = (const float*)d_in[6];
  const float* W_enc  = (const float*)d_in[7];
  const float* b_enc  = (const float*)d_in[8];
  const float* W_out  = (const float*)d_in[9];
  const float* W_vis  = (const float*)d_in[10];
  float* out = (float*)d_out;

  char* w = (char*)d_ws;
  auto alloc = [&](size_t bytes) { char* p = w; w += (bytes + 255) & ~(size_t)255; return p; };
  ushortT* xs_enc  = (ushortT*)alloc((size_t)L_ * B_ * EP_ * 2);
  ushortT* xs_dec  = (ushortT*)alloc((size_t)L_ * B_ * EP_ * 2);
  ushortT* Whhbf   = (ushortT*)alloc((size_t)G4_ * H_ * 2);
  ushortT* Wihbf   = (ushortT*)alloc((size_t)G4_ * EP_ * 2);
  float*   biasc   = (float*)  alloc((size_t)G4_ * 4);
  ushortT* Wvisbf  = (ushortT*)alloc((size_t)H_ * VIS_ * 2);
  ushortT* Wencbf  = (ushortT*)alloc((size_t)H_ * H_ * 2);
  ushortT* Woutbf  = (ushortT*)alloc((size_t)V_ * H_ * 2);
  ushortT* visbf   = (ushortT*)alloc((size_t)B_ * VIS_ * 2);
  ushortT* henc0   = (ushortT*)alloc((size_t)B_ * H_ * 2);
  ushortT* henc1   = (ushortT*)alloc((size_t)B_ * H_ * 2);
  float*   cenc    = (float*)  alloc((size_t)B_ * H_ * 4);
  ushortT* selbf   = (ushortT*)alloc((size_t)B_ * H_ * 2);
  ushortT* vbf     = (ushortT*)alloc((size_t)B_ * H_ * 2);
  ushortT* tencbf  = (ushortT*)alloc((size_t)B_ * H_ * 2);
  ushortT* Pbf     = (ushortT*)alloc((size_t)B_ * B_ * 2);
  ushortT* Vtbf    = (ushortT*)alloc((size_t)H_ * B_ * 2);
  float*   hatt    = (float*)  alloc((size_t)B_ * H_ * 4);
  float*   cdec    = (float*)  alloc((size_t)B_ * H_ * 4);
  ushortT* hdec0   = (ushortT*)alloc((size_t)B_ * H_ * 2);
  ushortT* hdec1   = (ushortT*)alloc((size_t)B_ * H_ * 2);
  int*     lens    = (int*)    alloc((size_t)B_ * 4);

  const int BH = B_ * H_;

  lengths_k<<<dim3((B_ + 255) / 256), dim3(256), 0, stream>>>(text, lens);
  stage_embs_k<<<dim3((L_ * B_ * EP_) / 256), dim3(256), 0, stream>>>(text, emb, xs_enc, xs_dec);

  prep_whh_k<<<dim3((G4_ * H_) / 256), dim3(256), 0, stream>>>(W_hh, Whhbf);
  prep_wih_k<<<dim3((G4_ * EP_) / 256), dim3(256), 0, stream>>>(W_ih, Wihbf);
  prep_bias_k<<<dim3(G4_ / 256), dim3(256), 0, stream>>>(b_ih, b_hh, biasc);
  cvt_k<<<dim3((H_ * VIS_) / 256), dim3(256), 0, stream>>>(W_vis, Wvisbf, H_ * VIS_);
  cvt_k<<<dim3((H_ * H_) / 256),   dim3(256), 0, stream>>>(W_enc, Wencbf, H_ * H_);
  cvt_k<<<dim3((V_ * H_) / 256),   dim3(256), 0, stream>>>(W_out, Woutbf, V_ * H_);
  cvt4_k<<<dim3((B_ * VIS_ / 4) / 256), dim3(256), 0, stream>>>(visual, visbf, B_ * VIS_ / 4);

  // visual projection -> vbf [B,H]
  gemm_bf16_k<<<dim3(H_ / 128, B_ / 128), dim3(256), 0, stream>>>(
      visbf, VIS_, VIS_, Wvisbf, VIS_, nullptr, nullptr, vbf, H_, 0);

  // encoder LSTM (fused cell epilogue, ping-pong h)
  fill_bf_k<<<dim3(BH / 256), dim3(256), 0, stream>>>(henc0, f2bf_h(0.1f), BH);
  fill_f_k<<<dim3(BH / 256), dim3(256), 0, stream>>>(cenc, 0.1f, BH);
  for (int t = 0; t < L_; ++t) {
    ushortT* hin  = (t & 1) ? henc1 : henc0;
    ushortT* hout = (t & 1) ? henc0 : henc1;
    lstm_gemm_k<<<dim3(G4_ / 128, B_ / 128), dim3(256), 0, stream>>>(
        hin, Whhbf, xs_enc + (size_t)t * B_ * EP_, Wihbf, biasc,
        cenc, hout, selbf, lens, t);
  }

  // enc linear + relu -> tencbf
  gemm_bf16_k<<<dim3(H_ / 128, B_ / 128), dim3(256), 0, stream>>>(
      selbf, H_, H_, Wencbf, H_, b_enc, nullptr, tencbf, H_, 1);

  // cosine attention
  rownorm_bf_k<<<dim3(B_), dim3(256), 0, stream>>>(vbf, H_);
  rownorm_bf_k<<<dim3(B_), dim3(256), 0, stream>>>(tencbf, H_);
  gemm_bf16_k<<<dim3(B_ / 128, B_ / 128), dim3(256), 0, stream>>>(
      tencbf, H_, H_, vbf, H_, nullptr, nullptr, Pbf, B_, 0);
  softmax_bf_rows_k<<<dim3(B_), dim3(256), 0, stream>>>(Pbf);
  transpose_bf_k<<<dim3(H_ / 32, B_ / 32), dim3(256), 0, stream>>>(vbf, Vtbf, B_, H_);
  gemm_bf16_k<<<dim3(H_ / 128, B_ / 128), dim3(256), 0, stream>>>(
      Pbf, B_, B_, Vtbf, B_, nullptr, hatt, nullptr, H_, 0);
  rownorm_fcb_k<<<dim3(B_), dim3(256), 0, stream>>>(hatt, hdec0, cdec, H_);

  // decoder LSTM + fused loss
  for (int t = 0; t < L_; ++t) {
    ushortT* hin  = (t & 1) ? hdec1 : hdec0;
    ushortT* hout = (t & 1) ? hdec0 : hdec1;
    lstm_gemm_k<<<dim3(G4_ / 128, B_ / 128), dim3(256), 0, stream>>>(
        hin, Whhbf, xs_dec + (size_t)t * B_ * EP_, Wihbf, biasc,
        cdec, hout, nullptr, nullptr, t);
    dec_loss_gemm_k<<<dim3(B_ / 128), dim3(256), 0, stream>>>(hout, Woutbf, text, t, out);
  }
}